// Round 19
// baseline (478.011 us; speedup 1.0000x reference)
//
#include <hip/hip_runtime.h>

#define NN 50000
#define NPAD 50176
#define EE 100000
#define HIDD 128
#define HH 4
#define CCC 128
#define HCC 512
#define QS 2048
#define LLL 3
#define SCALE 0.08838834764831845f

typedef unsigned short u16;
typedef unsigned int u32;
typedef __attribute__((ext_vector_type(8))) short bfrag;
typedef __attribute__((ext_vector_type(4))) float fx4;

__device__ __forceinline__ float bfl(u32 u){ return __uint_as_float(u << 16); }
__device__ __forceinline__ float bfh(u32 u){ return __uint_as_float(u & 0xffff0000u); }
__device__ __forceinline__ float bf1(u16 u){ return __uint_as_float((u32)u << 16); }
__device__ __forceinline__ u16 f2bf(float f){
  u32 u = __float_as_uint(f);
  return (u16)((u + 0x7fffu + ((u >> 16) & 1u)) >> 16);
}
__device__ __forceinline__ u32 pack2(float a, float b){
  return (u32)f2bf(a) | ((u32)f2bf(b) << 16);
}

union bfcvt { bfrag f; uint4 u; };

#if defined(__has_builtin)
#if __has_builtin(__builtin_amdgcn_global_load_lds)
#define USE_GLL 1
#endif
#endif
#ifndef USE_GLL
#define USE_GLL 0
#endif

__device__ __forceinline__ void gll16(const u16* g, u16* l){
#if USE_GLL
  __builtin_amdgcn_global_load_lds(
      (const __attribute__((address_space(1))) unsigned int*)(const void*)g,
      (__attribute__((address_space(3))) unsigned int*)(void*)l, 16, 0, 0);
#else
  uint4 v = *(const uint4*)g;
  *(uint4*)l = v;
#endif
}

__global__ __launch_bounds__(256) void kzero(int* p, int n){
  int i = blockIdx.x * 256 + threadIdx.x;
  if (i < n) p[i] = 0;
}

__global__ __launch_bounds__(256) void kcvt(const float* __restrict__ x,
                                            u16* __restrict__ xb){
  int i = blockIdx.x * 256 + threadIdx.x;
  if (i >= NPAD*HIDD/4) return;
  int base = i * 4;
  uint2 o = make_uint2(0u, 0u);
  if (base < NN*HIDD) {
    float4 v = *(const float4*)(x + base);
    o = make_uint2(pack2(v.x,v.y), pack2(v.z,v.w));
  }
  *(uint2*)(xb + base) = o;
}

// ---------------- CSR build ----------------
__global__ __launch_bounds__(256) void khist(const int* __restrict__ ei, int* __restrict__ counts){
  int e = blockIdx.x * 256 + threadIdx.x;
  if (e < EE) atomicAdd(&counts[ei[EE + e]], 1);
}

__global__ __launch_bounds__(256) void kscanA(const int* __restrict__ counts, int* __restrict__ bsum){
  __shared__ int sh[256];
  int t = threadIdx.x, i = blockIdx.x * 256 + t;
  sh[t] = (i < NN) ? counts[i] : 0;
  __syncthreads();
  #pragma unroll
  for (int off = 128; off; off >>= 1) {
    if (t < off) sh[t] += sh[t + off];
    __syncthreads();
  }
  if (t == 0) bsum[blockIdx.x] = sh[0];
}

__global__ __launch_bounds__(256) void kscanB(int* __restrict__ bsum, int nb){
  __shared__ int sh[256];
  int t = threadIdx.x;
  int v = (t < nb) ? bsum[t] : 0;
  sh[t] = v;
  __syncthreads();
  #pragma unroll
  for (int off = 1; off < 256; off <<= 1) {
    int a = (t >= off) ? sh[t - off] : 0;
    __syncthreads();
    sh[t] += a;
    __syncthreads();
  }
  if (t < nb) bsum[t] = sh[t] - v;
}

__global__ __launch_bounds__(256) void kscanC(const int* __restrict__ counts,
                                              const int* __restrict__ bsum,
                                              int* __restrict__ rowptr){
  __shared__ int sh[256];
  int t = threadIdx.x, i = blockIdx.x * 256 + t;
  int v = (i < NN) ? counts[i] : 0;
  sh[t] = v;
  __syncthreads();
  #pragma unroll
  for (int off = 1; off < 256; off <<= 1) {
    int a = (t >= off) ? sh[t - off] : 0;
    __syncthreads();
    sh[t] += a;
    __syncthreads();
  }
  if (i <= NN) rowptr[i] = bsum[blockIdx.x] + sh[t] - v;
}

__global__ __launch_bounds__(256) void kscatter(const int* __restrict__ ei,
                                                const float* __restrict__ ea,
                                                const int* __restrict__ rowptr,
                                                int* __restrict__ fill,
                                                int* __restrict__ csr_src,
                                                float* __restrict__ csr_ea){
  int e = blockIdx.x * 256 + threadIdx.x;
  if (e >= EE) return;
  int d = ei[EE + e];
  int pos = rowptr[d] + atomicAdd(&fill[d], 1);
  csr_src[pos] = ei[e];
  csr_ea[pos]  = ea[e];
}

// ---------------- weight prep (all 3 layers, hoisted) -----------------
__global__ __launch_bounds__(256) void kprep(
    const float* __restrict__ Wq, const float* __restrict__ Wk,
    const float* __restrict__ Wv,
    const float* __restrict__ bq, const float* __restrict__ bk,
    const float* __restrict__ bv,
    const float* __restrict__ Wp,
    u16* __restrict__ Wt3, u16* __restrict__ Wpt3, float* __restrict__ biasc3)
{
  const int l = blockIdx.y;
  const size_t wo = (size_t)l*HIDD*HCC;
  u16* Wt  = Wt3  + (size_t)l*1536*128;
  u16* Wpt = Wpt3 + (size_t)l*128*512;
  float* bias_cat = biasc3 + (size_t)l*1536;
  int id = blockIdx.x * 256 + threadIdx.x;
  if (id < 1536*128) {
    int n = id >> 7, k = id & 127;
    int m = n >> 9, nc = n & 511;
    const float* W = ((m==0)?Wq:(m==1)?Wk:Wv) + wo;
    Wt[id] = f2bf(W[(size_t)k*HCC + nc]);
  } else if (id < 1536*128 + 128*512) {
    int j = id - 1536*128;
    int n = j >> 9, k = j & 511;
    Wpt[j] = f2bf(Wp[wo + (size_t)k*HIDD + n]);
  } else if (id < 1536*128 + 128*512 + 1536) {
    int n = id - (1536*128 + 128*512);
    int m = n >> 9, nc = n & 511;
    const float* b = ((m==0)?bq:(m==1)?bk:bv) + (size_t)l*HCC;
    bias_cat[n] = b[nc];
  }
}

__global__ __launch_bounds__(256) void kskp2(
    const float* __restrict__ Wsk, const u16* __restrict__ Wpt3,
    u16* __restrict__ Wskt3)
{
  const int l = blockIdx.z;
  const float* WskL = Wsk + (size_t)l*HIDD*HCC;
  const u16* Wpt = Wpt3 + (size_t)l*128*512;
  u16* Wskt = Wskt3 + (size_t)l*128*128;
  const int t = threadIdx.x;
  const int wave = t >> 6, lane = t & 63;
  const int lo = lane & 15, hi = lane >> 4;
  const int wr = wave >> 1, wc = wave & 1;
  const int b0 = blockIdx.x * 64 + wr * 32;
  const int a0 = blockIdx.y * 32 + wc * 16;

  fx4 acc[2] = {};
  #pragma unroll
  for (int kk = 0; kk < 16; ++kk) {
    const float* wp = WskL + (size_t)(a0 + lo)*HCC + kk*32 + hi*8;
    float4 u = *(const float4*)(wp);
    float4 w = *(const float4*)(wp + 4);
    bfcvt bc;
    bc.u = make_uint4(pack2(u.x,u.y), pack2(u.z,u.w),
                      pack2(w.x,w.y), pack2(w.z,w.w));
    #pragma unroll
    for (int fr = 0; fr < 2; ++fr) {
      bfrag af = *(const bfrag*)(Wpt + (size_t)(b0 + fr*16 + lo)*HCC + kk*32 + hi*8);
      acc[fr] = __builtin_amdgcn_mfma_f32_16x16x32_bf16(af, bc.f, acc[fr], 0, 0, 0);
    }
  }
  #pragma unroll
  for (int fr = 0; fr < 2; ++fr)
    #pragma unroll
    for (int j = 0; j < 4; ++j)
      Wskt[(size_t)(b0 + fr*16 + hi*4 + j)*128 + a0 + lo] = f2bf(acc[fr][j]);
}

__global__ __launch_bounds__(256) void kbpe(
    const float* __restrict__ bsk, const float* __restrict__ Wp,
    const float* __restrict__ bp, float* __restrict__ bpe3)
{
  __shared__ float part[8][32];
  const int l = blockIdx.y;
  const float* bskL = bsk + (size_t)l*HCC;
  const float* WpL  = Wp  + (size_t)l*HCC*HIDD;
  const int c = blockIdx.x * 32 + (threadIdx.x & 31);
  const int seg = threadIdx.x >> 5;
  float s = 0.f;
  #pragma unroll
  for (int j = 0; j < 64; ++j)
    s += bskL[seg*64 + j] * WpL[(size_t)(seg*64 + j)*HIDD + c];
  part[seg][threadIdx.x & 31] = s;
  __syncthreads();
  if (seg == 0) {
    float tot = bp[(size_t)l*HIDD + c];
    #pragma unroll
    for (int k = 0; k < 8; ++k) tot += part[k][threadIdx.x & 31];
    bpe3[(size_t)l*HIDD + c] = tot;
  }
}

// K1: qkvs[N, 0..1536) = bf16( xb[N,128] @ Wt^T + bias )
// A rolling-prefetched to registers; B double-buffered LDS via gll16.
// 128x128 tile, 4 waves, BK=32 x 4; stride-132 epilogue; XCD swizzle.
__global__ __launch_bounds__(256) void k1_mfma(
    const u16* __restrict__ xb, const u16* __restrict__ Wt,
    const float* __restrict__ bias, u16* __restrict__ qkvs)
{
  __shared__ u16 lds[16896];   // B staging: [2][4096] at 0; epilogue [128][132]
  const int t = threadIdx.x;
  const int wave = t >> 6, lane = t & 63;
  const int lo = lane & 15, hi = lane >> 4;
  const int wr = wave >> 1, wc = wave & 1;

  int b = blockIdx.x;
  const int qq = 4692/8, rr = 4692%8;
  int xcd = b & 7, slot = b >> 3;
  int wgid = (xcd < rr ? xcd*(qq+1) : rr*(qq+1) + (xcd-rr)*qq) + slot;
  const int rb = (wgid / 12) * 128;
  const int cb = (wgid % 12) * 128;

  auto STAGE_B = [&](int buf, int kk){
    #pragma unroll
    for (int half = 0; half < 2; ++half) {
      int c = wave*64 + lane + half*256;
      int row = c >> 2, seg = c & 3;
#if USE_GLL
      gll16(Wt + (size_t)(cb + row)*HIDD + kk*32 + seg*8,
            &lds[buf*4096 + (wave*64 + half*256)*8]);
#else
      *(uint4*)&lds[buf*4096 + c*8] = *(const uint4*)(Wt + (size_t)(cb + row)*HIDD + kk*32 + seg*8);
#endif
    }
  };
  auto LDA = [&](int kk, bfrag* dst){
    #pragma unroll
    for (int fr = 0; fr < 4; ++fr) {
      bfcvt cv;
      cv.u = *(const uint4*)(xb + (size_t)(rb + wr*64 + fr*16 + lo)*HIDD + kk*32 + hi*8);
      dst[fr] = cv.f;
    }
  };

  fx4 acc[4][4] = {};
  bfrag aCur[4], aNxt[4];

  LDA(0, aCur);
  STAGE_B(0, 0);
  __syncthreads();
  #pragma unroll
  for (int kk = 0; kk < 4; ++kk) {
    const int buf = kk & 1;
    if (kk < 3) { LDA(kk + 1, aNxt); STAGE_B(buf ^ 1, kk + 1); }
    bfrag b2[4];
    #pragma unroll
    for (int fc = 0; fc < 4; ++fc)
      b2[fc] = *(const bfrag*)&lds[buf*4096 + (wc*64 + fc*16 + lo)*32 + hi*8];
    #pragma unroll
    for (int fr = 0; fr < 4; ++fr)
      #pragma unroll
      for (int fc = 0; fc < 4; ++fc)
        acc[fr][fc] = __builtin_amdgcn_mfma_f32_16x16x32_bf16(aCur[fr], b2[fc], acc[fr][fc], 0, 0, 0);
    __syncthreads();
    #pragma unroll
    for (int fr = 0; fr < 4; ++fr) aCur[fr] = aNxt[fr];
  }

  float bb[4];
  #pragma unroll
  for (int fc = 0; fc < 4; ++fc) bb[fc] = bias[cb + wc*64 + fc*16 + lo];
  #pragma unroll
  for (int fr = 0; fr < 4; ++fr)
    #pragma unroll
    for (int fc = 0; fc < 4; ++fc)
      #pragma unroll
      for (int j = 0; j < 4; ++j)
        lds[(size_t)(wr*64 + fr*16 + hi*4 + j)*132 + wc*64 + fc*16 + lo]
            = f2bf(acc[fr][fc][j] + bb[fc]);
  __syncthreads();

  #pragma unroll
  for (int i = 0; i < 8; ++i) {
    int f = t + 256*i;
    int row = f >> 4, seg = f & 15;
    if (rb + row < NN)
      *(uint4*)(qkvs + (size_t)(rb+row)*QS + cb + seg*8) = *(uint4*)&lds[(size_t)row*132 + seg*8];
  }
}

// K23: fused edge attention per dst node (one wave per node).
__global__ __launch_bounds__(256) void k23_fused(
    u16* __restrict__ qkvs, const int* __restrict__ rowptr,
    const int* __restrict__ csr_src, const float* __restrict__ csr_ea,
    const float* __restrict__ We)
{
  int wave = threadIdx.x >> 6, lane = threadIdx.x & 63;
  int n = blockIdx.x * 4 + wave;
  if (n >= NN) return;
  int h = lane >> 4, c0 = (lane & 15) * 8;

  uint4 qa = *(const uint4*)(qkvs + (size_t)n*QS + h*CCC + c0);
  float qf[8] = {bfl(qa.x),bfh(qa.x),bfl(qa.y),bfh(qa.y),
                 bfl(qa.z),bfh(qa.z),bfl(qa.w),bfh(qa.w)};
  float4 w0 = *(const float4*)(We + h*CCC + c0);
  float4 w1 = *(const float4*)(We + h*CCC + c0 + 4);
  float wf[8] = {w0.x,w0.y,w0.z,w0.w,w1.x,w1.y,w1.z,w1.w};

  float qw = qf[0]*wf[0]+qf[1]*wf[1]+qf[2]*wf[2]+qf[3]*wf[3]
           + qf[4]*wf[4]+qf[5]*wf[5]+qf[6]*wf[6]+qf[7]*wf[7];
  #pragma unroll
  for (int off = 8; off; off >>= 1) qw += __shfl_xor(qw, off);

  int beg = rowptr[n], end = rowptr[n+1];
  float accv[8] = {};
  float accp = 0.f, accw = 0.f;

  for (int i = beg; i < end; ++i) {
    int src = csr_src[i];
    float eav = csr_ea[i];
    uint4 ka = *(const uint4*)(qkvs + (size_t)src*QS + 512 + h*CCC + c0);
    float s = qf[0]*bfl(ka.x) + qf[1]*bfh(ka.x)
            + qf[2]*bfl(ka.y) + qf[3]*bfh(ka.y)
            + qf[4]*bfl(ka.z) + qf[5]*bfh(ka.z)
            + qf[6]*bfl(ka.w) + qf[7]*bfh(ka.w);
    #pragma unroll
    for (int off = 8; off; off >>= 1) s += __shfl_xor(s, off);
    float p = expf((s + eav * qw) * SCALE);
    uint4 va = *(const uint4*)(qkvs + (size_t)src*QS + 1024 + h*CCC + c0);
    accv[0] += p*bfl(va.x); accv[1] += p*bfh(va.x);
    accv[2] += p*bfl(va.y); accv[3] += p*bfh(va.y);
    accv[4] += p*bfl(va.z); accv[5] += p*bfh(va.z);
    accv[6] += p*bfl(va.w); accv[7] += p*bfh(va.w);
    accp += p; accw += p*eav;
  }

  float inv = 1.f / (accp + 1e-16f);
  float se  = accw * inv;
  u16* ap = qkvs + (size_t)n*QS + 1536 + h*CCC + c0;
  *(uint4*)ap = make_uint4(
    pack2(accv[0]*inv+se*wf[0], accv[1]*inv+se*wf[1]),
    pack2(accv[2]*inv+se*wf[2], accv[3]*inv+se*wf[3]),
    pack2(accv[4]*inv+se*wf[4], accv[5]*inv+se*wf[5]),
    pack2(accv[6]*inv+se*wf[6], accv[7]*inv+se*wf[7]));
}

// K4 (K=640, 32-row tiles): A rolling-prefetched to regs; B LDS dbuf.
__global__ __launch_bounds__(256) void k4_mfma(
    const u16* __restrict__ qkvs, const u16* __restrict__ xb_in,
    const u16* __restrict__ Wpt, const u16* __restrict__ Wskt,
    const float* __restrict__ bpe,
    const float* __restrict__ gamma, const float* __restrict__ beta,
    float* __restrict__ x_out, u16* __restrict__ xb_out, int last)
{
  __shared__ __align__(16) u16 lds[8448];    // B [2][4096]; reused as yt [32][132] f32
  __shared__ float mu_s[32], rs_s[32];
  float* yt = (float*)lds;
  const int t = threadIdx.x;
  const int wave = t >> 6, lane = t & 63;
  const int lo = lane & 15, hi = lane >> 4;
  const int wr = wave >> 1, wc = wave & 1;
  const int rb = blockIdx.x * 32;
  const int arow = rb + wr*16 + lo;

  auto STAGE_B = [&](int buf, int kk){
    #pragma unroll
    for (int half = 0; half < 2; ++half) {
      int c = wave*64 + lane + half*256;
      int col = c >> 2, seg = c & 3;
      const u16* src = (kk < 16)
        ? Wpt  + (size_t)col*512 + kk*32 + seg*8
        : Wskt + (size_t)col*128 + (kk-16)*32 + seg*8;
#if USE_GLL
      gll16(src, &lds[buf*4096 + (wave*64 + half*256)*8]);
#else
      *(uint4*)&lds[buf*4096 + c*8] = *(const uint4*)src;
#endif
    }
  };
  auto LDA = [&](int kk)->bfrag{
    const u16* src = (kk < 16)
      ? qkvs + (size_t)arow*QS + 1536 + kk*32 + hi*8
      : xb_in + (size_t)arow*HIDD + (kk-16)*32 + hi*8;
    bfcvt cv; cv.u = *(const uint4*)src; return cv.f;
  };

  fx4 acc[4] = {};
  bfrag aCur, aNxt;

  aCur = LDA(0);
  STAGE_B(0, 0);
  __syncthreads();
  #pragma unroll
  for (int kk = 0; kk < 20; ++kk) {
    const int buf = kk & 1;
    if (kk < 19) { aNxt = LDA(kk + 1); STAGE_B(buf ^ 1, kk + 1); }
    bfrag b[4];
    #pragma unroll
    for (int fc = 0; fc < 4; ++fc)
      b[fc] = *(const bfrag*)&lds[buf*4096 + (wc*64 + fc*16 + lo)*32 + hi*8];
    #pragma unroll
    for (int fc = 0; fc < 4; ++fc)
      acc[fc] = __builtin_amdgcn_mfma_f32_16x16x32_bf16(aCur, b[fc], acc[fc], 0, 0, 0);
    __syncthreads();
    aCur = aNxt;
  }

  // epilogue: bias + ELU + bf16 residual -> yt (LDS reused after barrier)
  float y[4][4];
  #pragma unroll
  for (int fc = 0; fc < 4; ++fc) {
    int col = wc*64 + fc*16 + lo;
    float bb = bpe[col];
    #pragma unroll
    for (int j = 0; j < 4; ++j) {
      int row = rb + wr*16 + hi*4 + j;
      float v = acc[fc][j] + bb;
      v = v > 0.f ? v : expm1f(v);
      float xv = (row < NN) ? bf1(xb_in[(size_t)row*HIDD + col]) : 0.f;
      y[fc][j] = xv + v;
    }
  }
  #pragma unroll
  for (int fc = 0; fc < 4; ++fc)
    #pragma unroll
    for (int j = 0; j < 4; ++j)
      yt[(size_t)(wr*16 + hi*4 + j)*132 + wc*64 + fc*16 + lo] = y[fc][j];
  __syncthreads();

  {
    int r = t >> 3, seg = t & 7;
    float s = 0.f, s2 = 0.f;
    #pragma unroll
    for (int j = 0; j < 16; ++j) {
      float v = yt[(size_t)r*132 + seg*16 + j];
      s += v; s2 += v*v;
    }
    #pragma unroll
    for (int off = 4; off; off >>= 1) { s += __shfl_xor(s, off); s2 += __shfl_xor(s2, off); }
    if (seg == 0) {
      float mu = s * (1.f/128.f);
      float var = s2 * (1.f/128.f) - mu*mu;
      mu_s[r] = mu;
      rs_s[r] = rsqrtf(var + 1e-5f);
    }
  }
  __syncthreads();

  #pragma unroll
  for (int i = 0; i < 4; ++i) {
    int f = t + 256*i;
    int r = f >> 5, c4 = (f & 31) * 4;
    int row = rb + r;
    if (row >= NN) continue;
    float mu = mu_s[r], rs = rs_s[r];
    float4 g  = *(const float4*)(gamma + c4);
    float4 bt = *(const float4*)(beta + c4);
    float4 yv = *(float4*)&yt[(size_t)r*132 + c4];
    float4 o = make_float4((yv.x-mu)*rs*g.x + bt.x, (yv.y-mu)*rs*g.y + bt.y,
                           (yv.z-mu)*rs*g.z + bt.z, (yv.w-mu)*rs*g.w + bt.w);
    *(uint2*)(xb_out + (size_t)row*HIDD + c4) = make_uint2(pack2(o.x,o.y), pack2(o.z,o.w));
    if (last) *(float4*)(x_out + (size_t)row*HIDD + c4) = o;
  }
}

extern "C" void kernel_launch(void* const* d_in, const int* in_sizes, int n_in,
                              void* d_out, int out_size, void* d_ws, size_t ws_size,
                              hipStream_t stream)
{
  const float* x    = (const float*)d_in[0];
  const int*   ei   = (const int*)d_in[1];
  const float* ea   = (const float*)d_in[2];
  const float* Wq   = (const float*)d_in[3];
  const float* bq   = (const float*)d_in[4];
  const float* Wk   = (const float*)d_in[5];
  const float* bk   = (const float*)d_in[6];
  const float* Wv   = (const float*)d_in[7];
  const float* bv   = (const float*)d_in[8];
  const float* We   = (const float*)d_in[9];
  const float* Wsk  = (const float*)d_in[10];
  const float* bsk  = (const float*)d_in[11];
  const float* Wp   = (const float*)d_in[12];
  const float* bp   = (const float*)d_in[13];
  const float* gamma= (const float*)d_in[14];
  const float* beta = (const float*)d_in[15];

  char* wsb = (char*)d_ws;
  size_t off = 0;
  auto alloc = [&](size_t bytes) -> void* {
    void* p = wsb + off;
    off += (bytes + 255) & ~(size_t)255;
    return p;
  };
  u16*   qkvs    = (u16*)  alloc((size_t)NPAD*QS*2);
  u16*   xb      = (u16*)  alloc((size_t)NPAD*HIDD*2);
  int*   rowptr  = (int*)  alloc((size_t)(NN+1)*4);
  int*   cntfill = (int*)  alloc((size_t)2*NN*4);    // counts | fill
  int*   counts  = cntfill;
  int*   fill    = cntfill + NN;
  int*   bsum    = (int*)  alloc((size_t)256*4);
  int*   csr_src = (int*)  alloc((size_t)EE*4);
  float* csr_ea  = (float*)alloc((size_t)EE*4);
  u16*   Wt3     = (u16*)  alloc((size_t)3*1536*128*2);
  u16*   Wpt3    = (u16*)  alloc((size_t)3*128*512*2);
  u16*   Wskt3   = (u16*)  alloc((size_t)3*128*128*2);
  float* biasc3  = (float*)alloc((size_t)3*1536*4);
  float* bpe3    = (float*)alloc((size_t)3*128*4);
  float* xio     = (float*)d_out;

  const int gn  = (NN + 255)/256;
  const int gz  = (2*NN + 255)/256;
  const int ge  = (EE + 255)/256;
  const int gc  = (NPAD*HIDD/4 + 255)/256;
  const dim3 gp((1536*128 + 128*512 + 1536 + 255)/256, 3);
  const dim3 gsk(2, 4, 3);
  const dim3 gbp(4, 3);
  const int g1  = 12 * ((NN + 127)/128);
  const int g23 = (NN + 3)/4;
  const int g4  = NPAD/32;

  // ---- one-time: CSR build, x->bf16, all-layer weight prep ----
  kzero<<<gz, 256, 0, stream>>>(cntfill, 2*NN);
  khist<<<ge, 256, 0, stream>>>(ei, counts);
  kscanA<<<gn, 256, 0, stream>>>(counts, bsum);
  kscanB<<<1, 256, 0, stream>>>(bsum, gn);
  kscanC<<<gn, 256, 0, stream>>>(counts, bsum, rowptr);
  kscatter<<<ge, 256, 0, stream>>>(ei, ea, rowptr, fill, csr_src, csr_ea);
  kcvt<<<gc, 256, 0, stream>>>(x, xb);
  kprep<<<gp, 256, 0, stream>>>(Wq, Wk, Wv, bq, bk, bv, Wp, Wt3, Wpt3, biasc3);
  kskp2<<<gsk, 256, 0, stream>>>(Wsk, Wpt3, Wskt3);
  kbpe<<<gbp, 256, 0, stream>>>(bsk, Wp, bp, bpe3);

  for (int l = 0; l < LLL; ++l) {
    const float* We_l = We + (size_t)l*HCC;
    const float* g_l  = gamma + (size_t)l*HIDD;
    const float* b_l  = beta  + (size_t)l*HIDD;

    k1_mfma<<<g1, 256, 0, stream>>>(xb, Wt3 + (size_t)l*1536*128,
                                    biasc3 + (size_t)l*1536, qkvs);
    k23_fused<<<g23, 256, 0, stream>>>(qkvs, rowptr, csr_src, csr_ea, We_l);
    k4_mfma<<<g4, 256, 0, stream>>>(qkvs, xb, Wpt3 + (size_t)l*128*512,
                                    Wskt3 + (size_t)l*128*128, bpe3 + (size_t)l*128,
                                    g_l, b_l, xio, xb, (l == LLL-1) ? 1 : 0);
  }
}

// Round 20
// 393.963 us; speedup vs baseline: 1.2133x; 1.2133x over previous
//
#include <hip/hip_runtime.h>

#define NN 50000
#define NPAD 50176
#define EE 100000
#define HIDD 128
#define HH 4
#define CCC 128
#define HCC 512
#define QS 2048
#define LLL 3
#define SCALE 0.08838834764831845f

typedef unsigned short u16;
typedef unsigned int u32;
typedef __attribute__((ext_vector_type(8))) short bfrag;
typedef __attribute__((ext_vector_type(4))) float fx4;

__device__ __forceinline__ float bfl(u32 u){ return __uint_as_float(u << 16); }
__device__ __forceinline__ float bfh(u32 u){ return __uint_as_float(u & 0xffff0000u); }
__device__ __forceinline__ float bf1(u16 u){ return __uint_as_float((u32)u << 16); }
__device__ __forceinline__ u16 f2bf(float f){
  u32 u = __float_as_uint(f);
  return (u16)((u + 0x7fffu + ((u >> 16) & 1u)) >> 16);
}
__device__ __forceinline__ u32 pack2(float a, float b){
  return (u32)f2bf(a) | ((u32)f2bf(b) << 16);
}

union bfcvt { bfrag f; uint4 u; };

#if defined(__has_builtin)
#if __has_builtin(__builtin_amdgcn_global_load_lds)
#define USE_GLL 1
#endif
#endif
#ifndef USE_GLL
#define USE_GLL 0
#endif

__device__ __forceinline__ void gll16(const u16* g, u16* l){
#if USE_GLL
  __builtin_amdgcn_global_load_lds(
      (const __attribute__((address_space(1))) unsigned int*)(const void*)g,
      (__attribute__((address_space(3))) unsigned int*)(void*)l, 16, 0, 0);
#else
  uint4 v = *(const uint4*)g;
  *(uint4*)l = v;
#endif
}

__global__ __launch_bounds__(256) void kzero(int* p, int n){
  int i = blockIdx.x * 256 + threadIdx.x;
  if (i < n) p[i] = 0;
}

__global__ __launch_bounds__(256) void kcvt(const float* __restrict__ x,
                                            u16* __restrict__ xb){
  int i = blockIdx.x * 256 + threadIdx.x;
  if (i >= NPAD*HIDD/4) return;
  int base = i * 4;
  uint2 o = make_uint2(0u, 0u);
  if (base < NN*HIDD) {
    float4 v = *(const float4*)(x + base);
    o = make_uint2(pack2(v.x,v.y), pack2(v.z,v.w));
  }
  *(uint2*)(xb + base) = o;
}

// ---------------- CSR build ----------------
__global__ __launch_bounds__(256) void khist(const int* __restrict__ ei, int* __restrict__ counts){
  int e = blockIdx.x * 256 + threadIdx.x;
  if (e < EE) atomicAdd(&counts[ei[EE + e]], 1);
}

__global__ __launch_bounds__(256) void kscanA(const int* __restrict__ counts, int* __restrict__ bsum){
  __shared__ int sh[256];
  int t = threadIdx.x, i = blockIdx.x * 256 + t;
  sh[t] = (i < NN) ? counts[i] : 0;
  __syncthreads();
  #pragma unroll
  for (int off = 128; off; off >>= 1) {
    if (t < off) sh[t] += sh[t + off];
    __syncthreads();
  }
  if (t == 0) bsum[blockIdx.x] = sh[0];
}

__global__ __launch_bounds__(256) void kscanB(int* __restrict__ bsum, int nb){
  __shared__ int sh[256];
  int t = threadIdx.x;
  int v = (t < nb) ? bsum[t] : 0;
  sh[t] = v;
  __syncthreads();
  #pragma unroll
  for (int off = 1; off < 256; off <<= 1) {
    int a = (t >= off) ? sh[t - off] : 0;
    __syncthreads();
    sh[t] += a;
    __syncthreads();
  }
  if (t < nb) bsum[t] = sh[t] - v;
}

__global__ __launch_bounds__(256) void kscanC(const int* __restrict__ counts,
                                              const int* __restrict__ bsum,
                                              int* __restrict__ rowptr){
  __shared__ int sh[256];
  int t = threadIdx.x, i = blockIdx.x * 256 + t;
  int v = (i < NN) ? counts[i] : 0;
  sh[t] = v;
  __syncthreads();
  #pragma unroll
  for (int off = 1; off < 256; off <<= 1) {
    int a = (t >= off) ? sh[t - off] : 0;
    __syncthreads();
    sh[t] += a;
    __syncthreads();
  }
  if (i <= NN) rowptr[i] = bsum[blockIdx.x] + sh[t] - v;
}

__global__ __launch_bounds__(256) void kscatter(const int* __restrict__ ei,
                                                const float* __restrict__ ea,
                                                const int* __restrict__ rowptr,
                                                int* __restrict__ fill,
                                                int* __restrict__ csr_src,
                                                float* __restrict__ csr_ea){
  int e = blockIdx.x * 256 + threadIdx.x;
  if (e >= EE) return;
  int d = ei[EE + e];
  int pos = rowptr[d] + atomicAdd(&fill[d], 1);
  csr_src[pos] = ei[e];
  csr_ea[pos]  = ea[e];
}

// ---------------- weight prep (all 3 layers, hoisted) -----------------
__global__ __launch_bounds__(256) void kprep(
    const float* __restrict__ Wq, const float* __restrict__ Wk,
    const float* __restrict__ Wv,
    const float* __restrict__ bq, const float* __restrict__ bk,
    const float* __restrict__ bv,
    const float* __restrict__ Wp,
    u16* __restrict__ Wt3, u16* __restrict__ Wpt3, float* __restrict__ biasc3)
{
  const int l = blockIdx.y;
  const size_t wo = (size_t)l*HIDD*HCC;
  u16* Wt  = Wt3  + (size_t)l*1536*128;
  u16* Wpt = Wpt3 + (size_t)l*128*512;
  float* bias_cat = biasc3 + (size_t)l*1536;
  int id = blockIdx.x * 256 + threadIdx.x;
  if (id < 1536*128) {
    int n = id >> 7, k = id & 127;
    int m = n >> 9, nc = n & 511;
    const float* W = ((m==0)?Wq:(m==1)?Wk:Wv) + wo;
    Wt[id] = f2bf(W[(size_t)k*HCC + nc]);
  } else if (id < 1536*128 + 128*512) {
    int j = id - 1536*128;
    int n = j >> 9, k = j & 511;
    Wpt[j] = f2bf(Wp[wo + (size_t)k*HIDD + n]);
  } else if (id < 1536*128 + 128*512 + 1536) {
    int n = id - (1536*128 + 128*512);
    int m = n >> 9, nc = n & 511;
    const float* b = ((m==0)?bq:(m==1)?bk:bv) + (size_t)l*HCC;
    bias_cat[n] = b[nc];
  }
}

__global__ __launch_bounds__(256) void kskp2(
    const float* __restrict__ Wsk, const u16* __restrict__ Wpt3,
    u16* __restrict__ Wskt3)
{
  const int l = blockIdx.z;
  const float* WskL = Wsk + (size_t)l*HIDD*HCC;
  const u16* Wpt = Wpt3 + (size_t)l*128*512;
  u16* Wskt = Wskt3 + (size_t)l*128*128;
  const int t = threadIdx.x;
  const int wave = t >> 6, lane = t & 63;
  const int lo = lane & 15, hi = lane >> 4;
  const int wr = wave >> 1, wc = wave & 1;
  const int b0 = blockIdx.x * 64 + wr * 32;
  const int a0 = blockIdx.y * 32 + wc * 16;

  fx4 acc[2] = {};
  #pragma unroll
  for (int kk = 0; kk < 16; ++kk) {
    const float* wp = WskL + (size_t)(a0 + lo)*HCC + kk*32 + hi*8;
    float4 u = *(const float4*)(wp);
    float4 w = *(const float4*)(wp + 4);
    bfcvt bc;
    bc.u = make_uint4(pack2(u.x,u.y), pack2(u.z,u.w),
                      pack2(w.x,w.y), pack2(w.z,w.w));
    #pragma unroll
    for (int fr = 0; fr < 2; ++fr) {
      bfrag af = *(const bfrag*)(Wpt + (size_t)(b0 + fr*16 + lo)*HCC + kk*32 + hi*8);
      acc[fr] = __builtin_amdgcn_mfma_f32_16x16x32_bf16(af, bc.f, acc[fr], 0, 0, 0);
    }
  }
  #pragma unroll
  for (int fr = 0; fr < 2; ++fr)
    #pragma unroll
    for (int j = 0; j < 4; ++j)
      Wskt[(size_t)(b0 + fr*16 + hi*4 + j)*128 + a0 + lo] = f2bf(acc[fr][j]);
}

__global__ __launch_bounds__(256) void kbpe(
    const float* __restrict__ bsk, const float* __restrict__ Wp,
    const float* __restrict__ bp, float* __restrict__ bpe3)
{
  __shared__ float part[8][32];
  const int l = blockIdx.y;
  const float* bskL = bsk + (size_t)l*HCC;
  const float* WpL  = Wp  + (size_t)l*HCC*HIDD;
  const int c = blockIdx.x * 32 + (threadIdx.x & 31);
  const int seg = threadIdx.x >> 5;
  float s = 0.f;
  #pragma unroll
  for (int j = 0; j < 64; ++j)
    s += bskL[seg*64 + j] * WpL[(size_t)(seg*64 + j)*HIDD + c];
  part[seg][threadIdx.x & 31] = s;
  __syncthreads();
  if (seg == 0) {
    float tot = bp[(size_t)l*HIDD + c];
    #pragma unroll
    for (int k = 0; k < 8; ++k) tot += part[k][threadIdx.x & 31];
    bpe3[(size_t)l*HIDD + c] = tot;
  }
}

// K1 (r18 form): qkvs[N, 0..1536) = bf16( xb[N,128] @ Wt^T + bias )
// 128x128 tile/block, 4 waves (64x64), BK=32 x 4 steps double-buffered,
// A+B staged via gll16; stride-132 epilogue; bijective XCD-chunked swizzle.
__global__ __launch_bounds__(256) void k1_mfma(
    const u16* __restrict__ xb, const u16* __restrict__ Wt,
    const float* __restrict__ bias, u16* __restrict__ qkvs)
{
  __shared__ u16 lds[16896];
  const int t = threadIdx.x;
  const int wave = t >> 6, lane = t & 63;
  const int lo = lane & 15, hi = lane >> 4;
  const int wr = wave >> 1, wc = wave & 1;

  int b = blockIdx.x;
  const int qq = 4692/8, rr = 4692%8;     // 586, 4
  int xcd = b & 7, slot = b >> 3;
  int wgid = (xcd < rr ? xcd*(qq+1) : rr*(qq+1) + (xcd-rr)*qq) + slot;
  const int rb = (wgid / 12) * 128;
  const int cb = (wgid % 12) * 128;

  auto STAGE = [&](int buf, int kk){
    #pragma unroll
    for (int half = 0; half < 2; ++half) {
      int c = wave*64 + lane + half*256;
      int row = c >> 2, seg = c & 3;
      gll16(xb + (size_t)(rb + row)*HIDD + kk*32 + seg*8,
            &lds[buf*4096 + (wave*64 + half*256)*8]);
    }
    #pragma unroll
    for (int half = 0; half < 2; ++half) {
      int c = wave*64 + lane + half*256;
      int row = c >> 2, seg = c & 3;
      gll16(Wt + (size_t)(cb + row)*HIDD + kk*32 + seg*8,
            &lds[8192 + buf*4096 + (wave*64 + half*256)*8]);
    }
  };

#if !USE_GLL
  auto STAGE_REG = [&](int buf, int kk){
    #pragma unroll
    for (int half = 0; half < 2; ++half) {
      int c = wave*64 + lane + half*256;
      int row = c >> 2, seg = c & 3;
      uint4 v = *(const uint4*)(xb + (size_t)(rb + row)*HIDD + kk*32 + seg*8);
      *(uint4*)&lds[buf*4096 + c*8] = v;
      uint4 w = *(const uint4*)(Wt + (size_t)(cb + row)*HIDD + kk*32 + seg*8);
      *(uint4*)&lds[8192 + buf*4096 + c*8] = w;
    }
  };
#define DO_STAGE STAGE_REG
#else
#define DO_STAGE STAGE
#endif

  fx4 acc[4][4] = {};

  DO_STAGE(0, 0);
  __syncthreads();
  #pragma unroll
  for (int kk = 0; kk < 4; ++kk) {
    const int buf = kk & 1;
    if (kk < 3) DO_STAGE(buf ^ 1, kk + 1);
    bfrag a[4], b2[4];
    #pragma unroll
    for (int fr = 0; fr < 4; ++fr)
      a[fr] = *(const bfrag*)&lds[buf*4096 + (wr*64 + fr*16 + lo)*32 + hi*8];
    #pragma unroll
    for (int fc = 0; fc < 4; ++fc)
      b2[fc] = *(const bfrag*)&lds[8192 + buf*4096 + (wc*64 + fc*16 + lo)*32 + hi*8];
    #pragma unroll
    for (int fr = 0; fr < 4; ++fr)
      #pragma unroll
      for (int fc = 0; fc < 4; ++fc)
        acc[fr][fc] = __builtin_amdgcn_mfma_f32_16x16x32_bf16(a[fr], b2[fc], acc[fr][fc], 0, 0, 0);
    __syncthreads();
  }

  float bb[4];
  #pragma unroll
  for (int fc = 0; fc < 4; ++fc) bb[fc] = bias[cb + wc*64 + fc*16 + lo];
  #pragma unroll
  for (int fr = 0; fr < 4; ++fr)
    #pragma unroll
    for (int fc = 0; fc < 4; ++fc)
      #pragma unroll
      for (int j = 0; j < 4; ++j)
        lds[(size_t)(wr*64 + fr*16 + hi*4 + j)*132 + wc*64 + fc*16 + lo]
            = f2bf(acc[fr][fc][j] + bb[fc]);
  __syncthreads();

  #pragma unroll
  for (int i = 0; i < 8; ++i) {
    int f = t + 256*i;
    int row = f >> 4, seg = f & 15;
    if (rb + row < NN)
      *(uint4*)(qkvs + (size_t)(rb+row)*QS + cb + seg*8) = *(uint4*)&lds[(size_t)row*132 + seg*8];
  }
}

// K23: fused edge attention per dst node (one wave per node).
__global__ __launch_bounds__(256) void k23_fused(
    u16* __restrict__ qkvs, const int* __restrict__ rowptr,
    const int* __restrict__ csr_src, const float* __restrict__ csr_ea,
    const float* __restrict__ We)
{
  int wave = threadIdx.x >> 6, lane = threadIdx.x & 63;
  int n = blockIdx.x * 4 + wave;
  if (n >= NN) return;
  int h = lane >> 4, c0 = (lane & 15) * 8;

  uint4 qa = *(const uint4*)(qkvs + (size_t)n*QS + h*CCC + c0);
  float qf[8] = {bfl(qa.x),bfh(qa.x),bfl(qa.y),bfh(qa.y),
                 bfl(qa.z),bfh(qa.z),bfl(qa.w),bfh(qa.w)};
  float4 w0 = *(const float4*)(We + h*CCC + c0);
  float4 w1 = *(const float4*)(We + h*CCC + c0 + 4);
  float wf[8] = {w0.x,w0.y,w0.z,w0.w,w1.x,w1.y,w1.z,w1.w};

  float qw = qf[0]*wf[0]+qf[1]*wf[1]+qf[2]*wf[2]+qf[3]*wf[3]
           + qf[4]*wf[4]+qf[5]*wf[5]+qf[6]*wf[6]+qf[7]*wf[7];
  #pragma unroll
  for (int off = 8; off; off >>= 1) qw += __shfl_xor(qw, off);

  int beg = rowptr[n], end = rowptr[n+1];
  float accv[8] = {};
  float accp = 0.f, accw = 0.f;

  for (int i = beg; i < end; ++i) {
    int src = csr_src[i];
    float eav = csr_ea[i];
    uint4 ka = *(const uint4*)(qkvs + (size_t)src*QS + 512 + h*CCC + c0);
    float s = qf[0]*bfl(ka.x) + qf[1]*bfh(ka.x)
            + qf[2]*bfl(ka.y) + qf[3]*bfh(ka.y)
            + qf[4]*bfl(ka.z) + qf[5]*bfh(ka.z)
            + qf[6]*bfl(ka.w) + qf[7]*bfh(ka.w);
    #pragma unroll
    for (int off = 8; off; off >>= 1) s += __shfl_xor(s, off);
    float p = expf((s + eav * qw) * SCALE);
    uint4 va = *(const uint4*)(qkvs + (size_t)src*QS + 1024 + h*CCC + c0);
    accv[0] += p*bfl(va.x); accv[1] += p*bfh(va.x);
    accv[2] += p*bfl(va.y); accv[3] += p*bfh(va.y);
    accv[4] += p*bfl(va.z); accv[5] += p*bfh(va.z);
    accv[6] += p*bfl(va.w); accv[7] += p*bfh(va.w);
    accp += p; accw += p*eav;
  }

  float inv = 1.f / (accp + 1e-16f);
  float se  = accw * inv;
  u16* ap = qkvs + (size_t)n*QS + 1536 + h*CCC + c0;
  *(uint4*)ap = make_uint4(
    pack2(accv[0]*inv+se*wf[0], accv[1]*inv+se*wf[1]),
    pack2(accv[2]*inv+se*wf[2], accv[3]*inv+se*wf[3]),
    pack2(accv[4]*inv+se*wf[4], accv[5]*inv+se*wf[5]),
    pack2(accv[6]*inv+se*wf[6], accv[7]*inv+se*wf[7]));
}

// K4 (r18 form, fused K=640, 32-row tiles): y = elu([conv|xb]@[Wpt;Wskt]+bpe)+xb ; LN
// 32x128 tile, 4 waves 2x2 (16x64 each, acc 4), BK=32 x 20 steps dbuf.
__global__ __launch_bounds__(256) void k4_mfma(
    const u16* __restrict__ qkvs, const u16* __restrict__ xb_in,
    const u16* __restrict__ Wpt, const u16* __restrict__ Wskt,
    const float* __restrict__ bpe,
    const float* __restrict__ gamma, const float* __restrict__ beta,
    float* __restrict__ x_out, u16* __restrict__ xb_out, int last)
{
  __shared__ __align__(16) u16 lds[10240];   // A [2][1024] at 0, B [2][4096] at 2048
  float* yt   = (float*)lds;                 // epilogue: [32][132] f32
  float* mu_s = (float*)&lds[8448];
  float* rs_s = (float*)&lds[8512];
  const int t = threadIdx.x;
  const int wave = t >> 6, lane = t & 63;
  const int lo = lane & 15, hi = lane >> 4;
  const int wr = wave >> 1, wc = wave & 1;
  const int rb = blockIdx.x * 32;

  auto STAGE = [&](int buf, int kk){
    if (wave < 2) {                           // A: 128 chunks (32 rows x 4 segs)
      int c = wave*64 + lane;
      int row = c >> 2, seg = c & 3;
      const u16* src = (kk < 16)
        ? qkvs + (size_t)(rb + row)*QS + 1536 + kk*32 + seg*8
        : xb_in + (size_t)(rb + row)*HIDD + (kk-16)*32 + seg*8;
#if USE_GLL
      gll16(src, &lds[buf*1024 + (wave*64)*8]);
#else
      *(uint4*)&lds[buf*1024 + c*8] = *(const uint4*)src;
#endif
    }
    #pragma unroll
    for (int half = 0; half < 2; ++half) {    // B: 512 chunks (128 cols x 4 segs)
      int c = wave*64 + lane + half*256;
      int col = c >> 2, seg = c & 3;
      const u16* src = (kk < 16)
        ? Wpt  + (size_t)col*512 + kk*32 + seg*8
        : Wskt + (size_t)col*128 + (kk-16)*32 + seg*8;
#if USE_GLL
      gll16(src, &lds[2048 + buf*4096 + (wave*64 + half*256)*8]);
#else
      *(uint4*)&lds[2048 + buf*4096 + c*8] = *(const uint4*)src;
#endif
    }
  };

  fx4 acc[4] = {};

  STAGE(0, 0);
  __syncthreads();
  #pragma unroll
  for (int kk = 0; kk < 20; ++kk) {
    const int buf = kk & 1;
    if (kk < 19) STAGE(buf ^ 1, kk + 1);
    bfrag a = *(const bfrag*)&lds[buf*1024 + (wr*16 + lo)*32 + hi*8];
    bfrag b[4];
    #pragma unroll
    for (int fc = 0; fc < 4; ++fc)
      b[fc] = *(const bfrag*)&lds[2048 + buf*4096 + (wc*64 + fc*16 + lo)*32 + hi*8];
    #pragma unroll
    for (int fc = 0; fc < 4; ++fc)
      acc[fc] = __builtin_amdgcn_mfma_f32_16x16x32_bf16(a, b[fc], acc[fc], 0, 0, 0);
    __syncthreads();
  }

  // epilogue: bias + ELU + bf16 residual (registers), then yt LDS for LN+stores
  float y[4][4];
  #pragma unroll
  for (int fc = 0; fc < 4; ++fc) {
    int col = wc*64 + fc*16 + lo;
    float bb = bpe[col];
    #pragma unroll
    for (int j = 0; j < 4; ++j) {
      int row = rb + wr*16 + hi*4 + j;
      float v = acc[fc][j] + bb;
      v = v > 0.f ? v : expm1f(v);
      float xv = (row < NN) ? bf1(xb_in[(size_t)row*HIDD + col]) : 0.f;
      y[fc][j] = xv + v;
    }
  }
  #pragma unroll
  for (int fc = 0; fc < 4; ++fc)
    #pragma unroll
    for (int j = 0; j < 4; ++j)
      yt[(size_t)(wr*16 + hi*4 + j)*132 + wc*64 + fc*16 + lo] = y[fc][j];
  __syncthreads();

  {
    int r = t >> 3, seg = t & 7;
    float s = 0.f, s2 = 0.f;
    #pragma unroll
    for (int j = 0; j < 16; ++j) {
      float v = yt[(size_t)r*132 + seg*16 + j];
      s += v; s2 += v*v;
    }
    #pragma unroll
    for (int off = 4; off; off >>= 1) { s += __shfl_xor(s, off); s2 += __shfl_xor(s2, off); }
    if (seg == 0) {
      float mu = s * (1.f/128.f);
      float var = s2 * (1.f/128.f) - mu*mu;
      mu_s[r] = mu;
      rs_s[r] = rsqrtf(var + 1e-5f);
    }
  }
  __syncthreads();

  #pragma unroll
  for (int i = 0; i < 4; ++i) {
    int f = t + 256*i;
    int r = f >> 5, c4 = (f & 31) * 4;
    int row = rb + r;
    if (row >= NN) continue;
    float mu = mu_s[r], rs = rs_s[r];
    float4 g  = *(const float4*)(gamma + c4);
    float4 bt = *(const float4*)(beta + c4);
    float4 yv = *(float4*)&yt[(size_t)r*132 + c4];
    float4 o = make_float4((yv.x-mu)*rs*g.x + bt.x, (yv.y-mu)*rs*g.y + bt.y,
                           (yv.z-mu)*rs*g.z + bt.z, (yv.w-mu)*rs*g.w + bt.w);
    *(uint2*)(xb_out + (size_t)row*HIDD + c4) = make_uint2(pack2(o.x,o.y), pack2(o.z,o.w));
    if (last) *(float4*)(x_out + (size_t)row*HIDD + c4) = o;
  }
}

extern "C" void kernel_launch(void* const* d_in, const int* in_sizes, int n_in,
                              void* d_out, int out_size, void* d_ws, size_t ws_size,
                              hipStream_t stream)
{
  const float* x    = (const float*)d_in[0];
  const int*   ei   = (const int*)d_in[1];
  const float* ea   = (const float*)d_in[2];
  const float* Wq   = (const float*)d_in[3];
  const float* bq   = (const float*)d_in[4];
  const float* Wk   = (const float*)d_in[5];
  const float* bk   = (const float*)d_in[6];
  const float* Wv   = (const float*)d_in[7];
  const float* bv   = (const float*)d_in[8];
  const float* We   = (const float*)d_in[9];
  const float* Wsk  = (const float*)d_in[10];
  const float* bsk  = (const float*)d_in[11];
  const float* Wp   = (const float*)d_in[12];
  const float* bp   = (const float*)d_in[13];
  const float* gamma= (const float*)d_in[14];
  const float* beta = (const float*)d_in[15];

  char* wsb = (char*)d_ws;
  size_t off = 0;
  auto alloc = [&](size_t bytes) -> void* {
    void* p = wsb + off;
    off += (bytes + 255) & ~(size_t)255;
    return p;
  };
  u16*   qkvs    = (u16*)  alloc((size_t)NPAD*QS*2);
  u16*   xb      = (u16*)  alloc((size_t)NPAD*HIDD*2);
  int*   rowptr  = (int*)  alloc((size_t)(NN+1)*4);
  int*   cntfill = (int*)  alloc((size_t)2*NN*4);    // counts | fill
  int*   counts  = cntfill;
  int*   fill    = cntfill + NN;
  int*   bsum    = (int*)  alloc((size_t)256*4);
  int*   csr_src = (int*)  alloc((size_t)EE*4);
  float* csr_ea  = (float*)alloc((size_t)EE*4);
  u16*   Wt3     = (u16*)  alloc((size_t)3*1536*128*2);
  u16*   Wpt3    = (u16*)  alloc((size_t)3*128*512*2);
  u16*   Wskt3   = (u16*)  alloc((size_t)3*128*128*2);
  float* biasc3  = (float*)alloc((size_t)3*1536*4);
  float* bpe3    = (float*)alloc((size_t)3*128*4);
  float* xio     = (float*)d_out;

  const int gn  = (NN + 255)/256;
  const int gz  = (2*NN + 255)/256;
  const int ge  = (EE + 255)/256;
  const int gc  = (NPAD*HIDD/4 + 255)/256;
  const dim3 gp((1536*128 + 128*512 + 1536 + 255)/256, 3);
  const dim3 gsk(2, 4, 3);
  const dim3 gbp(4, 3);
  const int g1  = 12 * ((NN + 127)/128);
  const int g23 = (NN + 3)/4;
  const int g4  = NPAD/32;

  // ---- one-time: CSR build, x->bf16, all-layer weight prep ----
  kzero<<<gz, 256, 0, stream>>>(cntfill, 2*NN);
  khist<<<ge, 256, 0, stream>>>(ei, counts);
  kscanA<<<gn, 256, 0, stream>>>(counts, bsum);
  kscanB<<<1, 256, 0, stream>>>(bsum, gn);
  kscanC<<<gn, 256, 0, stream>>>(counts, bsum, rowptr);
  kscatter<<<ge, 256, 0, stream>>>(ei, ea, rowptr, fill, csr_src, csr_ea);
  kcvt<<<gc, 256, 0, stream>>>(x, xb);
  kprep<<<gp, 256, 0, stream>>>(Wq, Wk, Wv, bq, bk, bv, Wp, Wt3, Wpt3, biasc3);
  kskp2<<<gsk, 256, 0, stream>>>(Wsk, Wpt3, Wskt3);
  kbpe<<<gbp, 256, 0, stream>>>(bsk, Wp, bp, bpe3);

  for (int l = 0; l < LLL; ++l) {
    const float* We_l = We + (size_t)l*HCC;
    const float* g_l  = gamma + (size_t)l*HIDD;
    const float* b_l  = beta  + (size_t)l*HIDD;

    k1_mfma<<<g1, 256, 0, stream>>>(xb, Wt3 + (size_t)l*1536*128,
                                    biasc3 + (size_t)l*1536, qkvs);
    k23_fused<<<g23, 256, 0, stream>>>(qkvs, rowptr, csr_src, csr_ea, We_l);
    k4_mfma<<<g4, 256, 0, stream>>>(qkvs, xb, Wpt3 + (size_t)l*128*512,
                                    Wskt3 + (size_t)l*128*128, bpe3 + (size_t)l*128,
                                    g_l, b_l, xio, xb, (l == LLL-1) ? 1 : 0);
  }
}

// Round 21
// 391.496 us; speedup vs baseline: 1.2210x; 1.0063x over previous
//
#include <hip/hip_runtime.h>

#define NN 50000
#define NPAD 50176
#define EE 100000
#define HIDD 128
#define HH 4
#define CCC 128
#define HCC 512
#define QS 2048
#define LLL 3
#define SCALE 0.08838834764831845f

typedef unsigned short u16;
typedef unsigned int u32;
typedef __attribute__((ext_vector_type(8))) short bfrag;
typedef __attribute__((ext_vector_type(4))) float fx4;

__device__ __forceinline__ float bfl(u32 u){ return __uint_as_float(u << 16); }
__device__ __forceinline__ float bfh(u32 u){ return __uint_as_float(u & 0xffff0000u); }
__device__ __forceinline__ float bf1(u16 u){ return __uint_as_float((u32)u << 16); }
__device__ __forceinline__ u16 f2bf(float f){
  u32 u = __float_as_uint(f);
  return (u16)((u + 0x7fffu + ((u >> 16) & 1u)) >> 16);
}
__device__ __forceinline__ u32 pack2(float a, float b){
  return (u32)f2bf(a) | ((u32)f2bf(b) << 16);
}

union bfcvt { bfrag f; uint4 u; };

#if defined(__has_builtin)
#if __has_builtin(__builtin_amdgcn_global_load_lds)
#define USE_GLL 1
#endif
#endif
#ifndef USE_GLL
#define USE_GLL 0
#endif

__device__ __forceinline__ void gll16(const u16* g, u16* l){
#if USE_GLL
  __builtin_amdgcn_global_load_lds(
      (const __attribute__((address_space(1))) unsigned int*)(const void*)g,
      (__attribute__((address_space(3))) unsigned int*)(void*)l, 16, 0, 0);
#else
  uint4 v = *(const uint4*)g;
  *(uint4*)l = v;
#endif
}

__global__ __launch_bounds__(256) void kzero(int* p, int n){
  int i = blockIdx.x * 256 + threadIdx.x;
  if (i < n) p[i] = 0;
}

__global__ __launch_bounds__(256) void kcvt(const float* __restrict__ x,
                                            u16* __restrict__ xb){
  int i = blockIdx.x * 256 + threadIdx.x;
  if (i >= NPAD*HIDD/4) return;
  int base = i * 4;
  uint2 o = make_uint2(0u, 0u);
  if (base < NN*HIDD) {
    float4 v = *(const float4*)(x + base);
    o = make_uint2(pack2(v.x,v.y), pack2(v.z,v.w));
  }
  *(uint2*)(xb + base) = o;
}

// ---------------- CSR build ----------------
__global__ __launch_bounds__(256) void khist(const int* __restrict__ ei, int* __restrict__ counts){
  int e = blockIdx.x * 256 + threadIdx.x;
  if (e < EE) atomicAdd(&counts[ei[EE + e]], 1);
}

__global__ __launch_bounds__(256) void kscanA(const int* __restrict__ counts, int* __restrict__ bsum){
  __shared__ int sh[256];
  int t = threadIdx.x, i = blockIdx.x * 256 + t;
  sh[t] = (i < NN) ? counts[i] : 0;
  __syncthreads();
  #pragma unroll
  for (int off = 128; off; off >>= 1) {
    if (t < off) sh[t] += sh[t + off];
    __syncthreads();
  }
  if (t == 0) bsum[blockIdx.x] = sh[0];
}

__global__ __launch_bounds__(256) void kscanB(int* __restrict__ bsum, int nb){
  __shared__ int sh[256];
  int t = threadIdx.x;
  int v = (t < nb) ? bsum[t] : 0;
  sh[t] = v;
  __syncthreads();
  #pragma unroll
  for (int off = 1; off < 256; off <<= 1) {
    int a = (t >= off) ? sh[t - off] : 0;
    __syncthreads();
    sh[t] += a;
    __syncthreads();
  }
  if (t < nb) bsum[t] = sh[t] - v;
}

__global__ __launch_bounds__(256) void kscanC(const int* __restrict__ counts,
                                              const int* __restrict__ bsum,
                                              int* __restrict__ rowptr){
  __shared__ int sh[256];
  int t = threadIdx.x, i = blockIdx.x * 256 + t;
  int v = (i < NN) ? counts[i] : 0;
  sh[t] = v;
  __syncthreads();
  #pragma unroll
  for (int off = 1; off < 256; off <<= 1) {
    int a = (t >= off) ? sh[t - off] : 0;
    __syncthreads();
    sh[t] += a;
    __syncthreads();
  }
  if (i <= NN) rowptr[i] = bsum[blockIdx.x] + sh[t] - v;
}

__global__ __launch_bounds__(256) void kscatter(const int* __restrict__ ei,
                                                const float* __restrict__ ea,
                                                const int* __restrict__ rowptr,
                                                int* __restrict__ fill,
                                                int* __restrict__ csr_src,
                                                float* __restrict__ csr_ea){
  int e = blockIdx.x * 256 + threadIdx.x;
  if (e >= EE) return;
  int d = ei[EE + e];
  int pos = rowptr[d] + atomicAdd(&fill[d], 1);
  csr_src[pos] = ei[e];
  csr_ea[pos]  = ea[e];
}

// ---------------- weight prep (all 3 layers, hoisted) -----------------
__global__ __launch_bounds__(256) void kprep(
    const float* __restrict__ Wq, const float* __restrict__ Wk,
    const float* __restrict__ Wv,
    const float* __restrict__ bq, const float* __restrict__ bk,
    const float* __restrict__ bv,
    const float* __restrict__ Wp,
    u16* __restrict__ Wt3, u16* __restrict__ Wpt3, float* __restrict__ biasc3)
{
  const int l = blockIdx.y;
  const size_t wo = (size_t)l*HIDD*HCC;
  u16* Wt  = Wt3  + (size_t)l*1536*128;
  u16* Wpt = Wpt3 + (size_t)l*128*512;
  float* bias_cat = biasc3 + (size_t)l*1536;
  int id = blockIdx.x * 256 + threadIdx.x;
  if (id < 1536*128) {
    int n = id >> 7, k = id & 127;
    int m = n >> 9, nc = n & 511;
    const float* W = ((m==0)?Wq:(m==1)?Wk:Wv) + wo;
    Wt[id] = f2bf(W[(size_t)k*HCC + nc]);
  } else if (id < 1536*128 + 128*512) {
    int j = id - 1536*128;
    int n = j >> 9, k = j & 511;
    Wpt[j] = f2bf(Wp[wo + (size_t)k*HIDD + n]);
  } else if (id < 1536*128 + 128*512 + 1536) {
    int n = id - (1536*128 + 128*512);
    int m = n >> 9, nc = n & 511;
    const float* b = ((m==0)?bq:(m==1)?bk:bv) + (size_t)l*HCC;
    bias_cat[n] = b[nc];
  }
}

__global__ __launch_bounds__(256) void kskp2(
    const float* __restrict__ Wsk, const u16* __restrict__ Wpt3,
    u16* __restrict__ Wskt3)
{
  const int l = blockIdx.z;
  const float* WskL = Wsk + (size_t)l*HIDD*HCC;
  const u16* Wpt = Wpt3 + (size_t)l*128*512;
  u16* Wskt = Wskt3 + (size_t)l*128*128;
  const int t = threadIdx.x;
  const int wave = t >> 6, lane = t & 63;
  const int lo = lane & 15, hi = lane >> 4;
  const int wr = wave >> 1, wc = wave & 1;
  const int b0 = blockIdx.x * 64 + wr * 32;
  const int a0 = blockIdx.y * 32 + wc * 16;

  fx4 acc[2] = {};
  #pragma unroll
  for (int kk = 0; kk < 16; ++kk) {
    const float* wp = WskL + (size_t)(a0 + lo)*HCC + kk*32 + hi*8;
    float4 u = *(const float4*)(wp);
    float4 w = *(const float4*)(wp + 4);
    bfcvt bc;
    bc.u = make_uint4(pack2(u.x,u.y), pack2(u.z,u.w),
                      pack2(w.x,w.y), pack2(w.z,w.w));
    #pragma unroll
    for (int fr = 0; fr < 2; ++fr) {
      bfrag af = *(const bfrag*)(Wpt + (size_t)(b0 + fr*16 + lo)*HCC + kk*32 + hi*8);
      acc[fr] = __builtin_amdgcn_mfma_f32_16x16x32_bf16(af, bc.f, acc[fr], 0, 0, 0);
    }
  }
  #pragma unroll
  for (int fr = 0; fr < 2; ++fr)
    #pragma unroll
    for (int j = 0; j < 4; ++j)
      Wskt[(size_t)(b0 + fr*16 + hi*4 + j)*128 + a0 + lo] = f2bf(acc[fr][j]);
}

__global__ __launch_bounds__(256) void kbpe(
    const float* __restrict__ bsk, const float* __restrict__ Wp,
    const float* __restrict__ bp, float* __restrict__ bpe3)
{
  __shared__ float part[8][32];
  const int l = blockIdx.y;
  const float* bskL = bsk + (size_t)l*HCC;
  const float* WpL  = Wp  + (size_t)l*HCC*HIDD;
  const int c = blockIdx.x * 32 + (threadIdx.x & 31);
  const int seg = threadIdx.x >> 5;
  float s = 0.f;
  #pragma unroll
  for (int j = 0; j < 64; ++j)
    s += bskL[seg*64 + j] * WpL[(size_t)(seg*64 + j)*HIDD + c];
  part[seg][threadIdx.x & 31] = s;
  __syncthreads();
  if (seg == 0) {
    float tot = bp[(size_t)l*HIDD + c];
    #pragma unroll
    for (int k = 0; k < 8; ++k) tot += part[k][threadIdx.x & 31];
    bpe3[(size_t)l*HIDD + c] = tot;
  }
}

// K1: qkvs[N, 0..1536) = bf16( xb[N,128] @ Wt^T + bias )
// 128x128 tile/block, 4 waves (64x64), BK=32 x 4 steps double-buffered,
// A+B staged via gll16; stride-132 epilogue; bijective XCD-chunked swizzle.
__global__ __launch_bounds__(256) void k1_mfma(
    const u16* __restrict__ xb, const u16* __restrict__ Wt,
    const float* __restrict__ bias, u16* __restrict__ qkvs)
{
  __shared__ u16 lds[16896];
  const int t = threadIdx.x;
  const int wave = t >> 6, lane = t & 63;
  const int lo = lane & 15, hi = lane >> 4;
  const int wr = wave >> 1, wc = wave & 1;

  int b = blockIdx.x;
  const int qq = 4692/8, rr = 4692%8;     // 586, 4
  int xcd = b & 7, slot = b >> 3;
  int wgid = (xcd < rr ? xcd*(qq+1) : rr*(qq+1) + (xcd-rr)*qq) + slot;
  const int rb = (wgid / 12) * 128;
  const int cb = (wgid % 12) * 128;

  auto STAGE = [&](int buf, int kk){
    #pragma unroll
    for (int half = 0; half < 2; ++half) {
      int c = wave*64 + lane + half*256;
      int row = c >> 2, seg = c & 3;
      gll16(xb + (size_t)(rb + row)*HIDD + kk*32 + seg*8,
            &lds[buf*4096 + (wave*64 + half*256)*8]);
    }
    #pragma unroll
    for (int half = 0; half < 2; ++half) {
      int c = wave*64 + lane + half*256;
      int row = c >> 2, seg = c & 3;
      gll16(Wt + (size_t)(cb + row)*HIDD + kk*32 + seg*8,
            &lds[8192 + buf*4096 + (wave*64 + half*256)*8]);
    }
  };

#if !USE_GLL
  auto STAGE_REG = [&](int buf, int kk){
    #pragma unroll
    for (int half = 0; half < 2; ++half) {
      int c = wave*64 + lane + half*256;
      int row = c >> 2, seg = c & 3;
      uint4 v = *(const uint4*)(xb + (size_t)(rb + row)*HIDD + kk*32 + seg*8);
      *(uint4*)&lds[buf*4096 + c*8] = v;
      uint4 w = *(const uint4*)(Wt + (size_t)(cb + row)*HIDD + kk*32 + seg*8);
      *(uint4*)&lds[8192 + buf*4096 + c*8] = w;
    }
  };
#define DO_STAGE STAGE_REG
#else
#define DO_STAGE STAGE
#endif

  fx4 acc[4][4] = {};

  DO_STAGE(0, 0);
  __syncthreads();
  #pragma unroll
  for (int kk = 0; kk < 4; ++kk) {
    const int buf = kk & 1;
    if (kk < 3) DO_STAGE(buf ^ 1, kk + 1);
    bfrag a[4], b2[4];
    #pragma unroll
    for (int fr = 0; fr < 4; ++fr)
      a[fr] = *(const bfrag*)&lds[buf*4096 + (wr*64 + fr*16 + lo)*32 + hi*8];
    #pragma unroll
    for (int fc = 0; fc < 4; ++fc)
      b2[fc] = *(const bfrag*)&lds[8192 + buf*4096 + (wc*64 + fc*16 + lo)*32 + hi*8];
    #pragma unroll
    for (int fr = 0; fr < 4; ++fr)
      #pragma unroll
      for (int fc = 0; fc < 4; ++fc)
        acc[fr][fc] = __builtin_amdgcn_mfma_f32_16x16x32_bf16(a[fr], b2[fc], acc[fr][fc], 0, 0, 0);
    __syncthreads();
  }

  float bb[4];
  #pragma unroll
  for (int fc = 0; fc < 4; ++fc) bb[fc] = bias[cb + wc*64 + fc*16 + lo];
  #pragma unroll
  for (int fr = 0; fr < 4; ++fr)
    #pragma unroll
    for (int fc = 0; fc < 4; ++fc)
      #pragma unroll
      for (int j = 0; j < 4; ++j)
        lds[(size_t)(wr*64 + fr*16 + hi*4 + j)*132 + wc*64 + fc*16 + lo]
            = f2bf(acc[fr][fc][j] + bb[fc]);
  __syncthreads();

  #pragma unroll
  for (int i = 0; i < 8; ++i) {
    int f = t + 256*i;
    int row = f >> 4, seg = f & 15;
    if (rb + row < NN)
      *(uint4*)(qkvs + (size_t)(rb+row)*QS + cb + seg*8) = *(uint4*)&lds[(size_t)row*132 + seg*8];
  }
}

// K23: fused edge attention per dst node (one wave per node).
// degree-0 early-out; pairwise-unrolled edge loop for memory-level parallelism.
__global__ __launch_bounds__(256) void k23_fused(
    u16* __restrict__ qkvs, const int* __restrict__ rowptr,
    const int* __restrict__ csr_src, const float* __restrict__ csr_ea,
    const float* __restrict__ We)
{
  int wave = threadIdx.x >> 6, lane = threadIdx.x & 63;
  int n = blockIdx.x * 4 + wave;
  if (n >= NN) return;
  int h = lane >> 4, c0 = (lane & 15) * 8;

  int beg = rowptr[n], end = rowptr[n+1];
  u16* ap = qkvs + (size_t)n*QS + 1536 + h*CCC + c0;

  if (beg == end) {            // no in-edges: conv row = 0 (skip folded into k4)
    *(uint4*)ap = make_uint4(0u,0u,0u,0u);
    return;
  }

  uint4 qa = *(const uint4*)(qkvs + (size_t)n*QS + h*CCC + c0);
  float qf[8] = {bfl(qa.x),bfh(qa.x),bfl(qa.y),bfh(qa.y),
                 bfl(qa.z),bfh(qa.z),bfl(qa.w),bfh(qa.w)};
  float4 w0 = *(const float4*)(We + h*CCC + c0);
  float4 w1 = *(const float4*)(We + h*CCC + c0 + 4);
  float wf[8] = {w0.x,w0.y,w0.z,w0.w,w1.x,w1.y,w1.z,w1.w};

  float qw = qf[0]*wf[0]+qf[1]*wf[1]+qf[2]*wf[2]+qf[3]*wf[3]
           + qf[4]*wf[4]+qf[5]*wf[5]+qf[6]*wf[6]+qf[7]*wf[7];
  #pragma unroll
  for (int off = 8; off; off >>= 1) qw += __shfl_xor(qw, off);

  float accv[8] = {};
  float accp = 0.f, accw = 0.f;

  int i = beg;
  for (; i + 2 <= end; i += 2) {
    int s0 = csr_src[i],   s1 = csr_src[i+1];
    float e0 = csr_ea[i],  e1 = csr_ea[i+1];
    uint4 ka0 = *(const uint4*)(qkvs + (size_t)s0*QS + 512 + h*CCC + c0);
    uint4 ka1 = *(const uint4*)(qkvs + (size_t)s1*QS + 512 + h*CCC + c0);
    float d0 = qf[0]*bfl(ka0.x) + qf[1]*bfh(ka0.x)
             + qf[2]*bfl(ka0.y) + qf[3]*bfh(ka0.y)
             + qf[4]*bfl(ka0.z) + qf[5]*bfh(ka0.z)
             + qf[6]*bfl(ka0.w) + qf[7]*bfh(ka0.w);
    float d1 = qf[0]*bfl(ka1.x) + qf[1]*bfh(ka1.x)
             + qf[2]*bfl(ka1.y) + qf[3]*bfh(ka1.y)
             + qf[4]*bfl(ka1.z) + qf[5]*bfh(ka1.z)
             + qf[6]*bfl(ka1.w) + qf[7]*bfh(ka1.w);
    #pragma unroll
    for (int off = 8; off; off >>= 1) {
      d0 += __shfl_xor(d0, off);
      d1 += __shfl_xor(d1, off);
    }
    uint4 va0 = *(const uint4*)(qkvs + (size_t)s0*QS + 1024 + h*CCC + c0);
    uint4 va1 = *(const uint4*)(qkvs + (size_t)s1*QS + 1024 + h*CCC + c0);
    float p0 = expf((d0 + e0 * qw) * SCALE);
    float p1 = expf((d1 + e1 * qw) * SCALE);
    accv[0] += p0*bfl(va0.x) + p1*bfl(va1.x);
    accv[1] += p0*bfh(va0.x) + p1*bfh(va1.x);
    accv[2] += p0*bfl(va0.y) + p1*bfl(va1.y);
    accv[3] += p0*bfh(va0.y) + p1*bfh(va1.y);
    accv[4] += p0*bfl(va0.z) + p1*bfl(va1.z);
    accv[5] += p0*bfh(va0.z) + p1*bfh(va1.z);
    accv[6] += p0*bfl(va0.w) + p1*bfl(va1.w);
    accv[7] += p0*bfh(va0.w) + p1*bfh(va1.w);
    accp += p0 + p1;
    accw += p0*e0 + p1*e1;
  }
  if (i < end) {
    int src = csr_src[i];
    float eav = csr_ea[i];
    uint4 ka = *(const uint4*)(qkvs + (size_t)src*QS + 512 + h*CCC + c0);
    float s = qf[0]*bfl(ka.x) + qf[1]*bfh(ka.x)
            + qf[2]*bfl(ka.y) + qf[3]*bfh(ka.y)
            + qf[4]*bfl(ka.z) + qf[5]*bfh(ka.z)
            + qf[6]*bfl(ka.w) + qf[7]*bfh(ka.w);
    #pragma unroll
    for (int off = 8; off; off >>= 1) s += __shfl_xor(s, off);
    float p = expf((s + eav * qw) * SCALE);
    uint4 va = *(const uint4*)(qkvs + (size_t)src*QS + 1024 + h*CCC + c0);
    accv[0] += p*bfl(va.x); accv[1] += p*bfh(va.x);
    accv[2] += p*bfl(va.y); accv[3] += p*bfh(va.y);
    accv[4] += p*bfl(va.z); accv[5] += p*bfh(va.z);
    accv[6] += p*bfl(va.w); accv[7] += p*bfh(va.w);
    accp += p; accw += p*eav;
  }

  float inv = 1.f / (accp + 1e-16f);
  float se  = accw * inv;
  *(uint4*)ap = make_uint4(
    pack2(accv[0]*inv+se*wf[0], accv[1]*inv+se*wf[1]),
    pack2(accv[2]*inv+se*wf[2], accv[3]*inv+se*wf[3]),
    pack2(accv[4]*inv+se*wf[4], accv[5]*inv+se*wf[5]),
    pack2(accv[6]*inv+se*wf[6], accv[7]*inv+se*wf[7]));
}

// K4 (fused K=640, 32-row tiles): y = elu([conv|xb]@[Wpt;Wskt]+bpe)+xb ; LN
// 32x128 tile, 4 waves 2x2 (16x64 each, acc 4), BK=32 x 20 steps dbuf.
__global__ __launch_bounds__(256) void k4_mfma(
    const u16* __restrict__ qkvs, const u16* __restrict__ xb_in,
    const u16* __restrict__ Wpt, const u16* __restrict__ Wskt,
    const float* __restrict__ bpe,
    const float* __restrict__ gamma, const float* __restrict__ beta,
    float* __restrict__ x_out, u16* __restrict__ xb_out, int last)
{
  __shared__ __align__(16) u16 lds[10240];   // A [2][1024] at 0, B [2][4096] at 2048
  float* yt   = (float*)lds;                 // epilogue: [32][132] f32
  float* mu_s = (float*)&lds[8448];
  float* rs_s = (float*)&lds[8512];
  const int t = threadIdx.x;
  const int wave = t >> 6, lane = t & 63;
  const int lo = lane & 15, hi = lane >> 4;
  const int wr = wave >> 1, wc = wave & 1;
  const int rb = blockIdx.x * 32;

  auto STAGE = [&](int buf, int kk){
    if (wave < 2) {                           // A: 128 chunks (32 rows x 4 segs)
      int c = wave*64 + lane;
      int row = c >> 2, seg = c & 3;
      const u16* src = (kk < 16)
        ? qkvs + (size_t)(rb + row)*QS + 1536 + kk*32 + seg*8
        : xb_in + (size_t)(rb + row)*HIDD + (kk-16)*32 + seg*8;
#if USE_GLL
      gll16(src, &lds[buf*1024 + (wave*64)*8]);
#else
      *(uint4*)&lds[buf*1024 + c*8] = *(const uint4*)src;
#endif
    }
    #pragma unroll
    for (int half = 0; half < 2; ++half) {    // B: 512 chunks (128 cols x 4 segs)
      int c = wave*64 + lane + half*256;
      int col = c >> 2, seg = c & 3;
      const u16* src = (kk < 16)
        ? Wpt  + (size_t)col*512 + kk*32 + seg*8
        : Wskt + (size_t)col*128 + (kk-16)*32 + seg*8;
#if USE_GLL
      gll16(src, &lds[2048 + buf*4096 + (wave*64 + half*256)*8]);
#else
      *(uint4*)&lds[2048 + buf*4096 + c*8] = *(const uint4*)src;
#endif
    }
  };

  fx4 acc[4] = {};

  STAGE(0, 0);
  __syncthreads();
  #pragma unroll
  for (int kk = 0; kk < 20; ++kk) {
    const int buf = kk & 1;
    if (kk < 19) STAGE(buf ^ 1, kk + 1);
    bfrag a = *(const bfrag*)&lds[buf*1024 + (wr*16 + lo)*32 + hi*8];
    bfrag b[4];
    #pragma unroll
    for (int fc = 0; fc < 4; ++fc)
      b[fc] = *(const bfrag*)&lds[2048 + buf*4096 + (wc*64 + fc*16 + lo)*32 + hi*8];
    #pragma unroll
    for (int fc = 0; fc < 4; ++fc)
      acc[fc] = __builtin_amdgcn_mfma_f32_16x16x32_bf16(a, b[fc], acc[fc], 0, 0, 0);
    __syncthreads();
  }

  // epilogue: bias + ELU + bf16 residual (registers), then yt LDS for LN+stores
  float y[4][4];
  #pragma unroll
  for (int fc = 0; fc < 4; ++fc) {
    int col = wc*64 + fc*16 + lo;
    float bb = bpe[col];
    #pragma unroll
    for (int j = 0; j < 4; ++j) {
      int row = rb + wr*16 + hi*4 + j;
      float v = acc[fc][j] + bb;
      v = v > 0.f ? v : expm1f(v);
      float xv = (row < NN) ? bf1(xb_in[(size_t)row*HIDD + col]) : 0.f;
      y[fc][j] = xv + v;
    }
  }
  #pragma unroll
  for (int fc = 0; fc < 4; ++fc)
    #pragma unroll
    for (int j = 0; j < 4; ++j)
      yt[(size_t)(wr*16 + hi*4 + j)*132 + wc*64 + fc*16 + lo] = y[fc][j];
  __syncthreads();

  {
    int r = t >> 3, seg = t & 7;
    float s = 0.f, s2 = 0.f;
    #pragma unroll
    for (int j = 0; j < 16; ++j) {
      float v = yt[(size_t)r*132 + seg*16 + j];
      s += v; s2 += v*v;
    }
    #pragma unroll
    for (int off = 4; off; off >>= 1) { s += __shfl_xor(s, off); s2 += __shfl_xor(s2, off); }
    if (seg == 0) {
      float mu = s * (1.f/128.f);
      float var = s2 * (1.f/128.f) - mu*mu;
      mu_s[r] = mu;
      rs_s[r] = rsqrtf(var + 1e-5f);
    }
  }
  __syncthreads();

  #pragma unroll
  for (int i = 0; i < 4; ++i) {
    int f = t + 256*i;
    int r = f >> 5, c4 = (f & 31) * 4;
    int row = rb + r;
    if (row >= NN) continue;
    float mu = mu_s[r], rs = rs_s[r];
    float4 g  = *(const float4*)(gamma + c4);
    float4 bt = *(const float4*)(beta + c4);
    float4 yv = *(float4*)&yt[(size_t)r*132 + c4];
    float4 o = make_float4((yv.x-mu)*rs*g.x + bt.x, (yv.y-mu)*rs*g.y + bt.y,
                           (yv.z-mu)*rs*g.z + bt.z, (yv.w-mu)*rs*g.w + bt.w);
    *(uint2*)(xb_out + (size_t)row*HIDD + c4) = make_uint2(pack2(o.x,o.y), pack2(o.z,o.w));
    if (last) *(float4*)(x_out + (size_t)row*HIDD + c4) = o;
  }
}

extern "C" void kernel_launch(void* const* d_in, const int* in_sizes, int n_in,
                              void* d_out, int out_size, void* d_ws, size_t ws_size,
                              hipStream_t stream)
{
  const float* x    = (const float*)d_in[0];
  const int*   ei   = (const int*)d_in[1];
  const float* ea   = (const float*)d_in[2];
  const float* Wq   = (const float*)d_in[3];
  const float* bq   = (const float*)d_in[4];
  const float* Wk   = (const float*)d_in[5];
  const float* bk   = (const float*)d_in[6];
  const float* Wv   = (const float*)d_in[7];
  const float* bv   = (const float*)d_in[8];
  const float* We   = (const float*)d_in[9];
  const float* Wsk  = (const float*)d_in[10];
  const float* bsk  = (const float*)d_in[11];
  const float* Wp   = (const float*)d_in[12];
  const float* bp   = (const float*)d_in[13];
  const float* gamma= (const float*)d_in[14];
  const float* beta = (const float*)d_in[15];

  char* wsb = (char*)d_ws;
  size_t off = 0;
  auto alloc = [&](size_t bytes) -> void* {
    void* p = wsb + off;
    off += (bytes + 255) & ~(size_t)255;
    return p;
  };
  u16*   qkvs    = (u16*)  alloc((size_t)NPAD*QS*2);
  u16*   xb      = (u16*)  alloc((size_t)NPAD*HIDD*2);
  int*   rowptr  = (int*)  alloc((size_t)(NN+1)*4);
  int*   cntfill = (int*)  alloc((size_t)2*NN*4);    // counts | fill
  int*   counts  = cntfill;
  int*   fill    = cntfill + NN;
  int*   bsum    = (int*)  alloc((size_t)256*4);
  int*   csr_src = (int*)  alloc((size_t)EE*4);
  float* csr_ea  = (float*)alloc((size_t)EE*4);
  u16*   Wt3     = (u16*)  alloc((size_t)3*1536*128*2);
  u16*   Wpt3    = (u16*)  alloc((size_t)3*128*512*2);
  u16*   Wskt3   = (u16*)  alloc((size_t)3*128*128*2);
  float* biasc3  = (float*)alloc((size_t)3*1536*4);
  float* bpe3    = (float*)alloc((size_t)3*128*4);
  float* xio     = (float*)d_out;

  const int gn  = (NN + 255)/256;
  const int gz  = (2*NN + 255)/256;
  const int ge  = (EE + 255)/256;
  const int gc  = (NPAD*HIDD/4 + 255)/256;
  const dim3 gp((1536*128 + 128*512 + 1536 + 255)/256, 3);
  const dim3 gsk(2, 4, 3);
  const dim3 gbp(4, 3);
  const int g1  = 12 * ((NN + 127)/128);
  const int g23 = (NN + 3)/4;
  const int g4  = NPAD/32;

  // ---- one-time: CSR build, x->bf16, all-layer weight prep ----
  kzero<<<gz, 256, 0, stream>>>(cntfill, 2*NN);
  khist<<<ge, 256, 0, stream>>>(ei, counts);
  kscanA<<<gn, 256, 0, stream>>>(counts, bsum);
  kscanB<<<1, 256, 0, stream>>>(bsum, gn);
  kscanC<<<gn, 256, 0, stream>>>(counts, bsum, rowptr);
  kscatter<<<ge, 256, 0, stream>>>(ei, ea, rowptr, fill, csr_src, csr_ea);
  kcvt<<<gc, 256, 0, stream>>>(x, xb);
  kprep<<<gp, 256, 0, stream>>>(Wq, Wk, Wv, bq, bk, bv, Wp, Wt3, Wpt3, biasc3);
  kskp2<<<gsk, 256, 0, stream>>>(Wsk, Wpt3, Wskt3);
  kbpe<<<gbp, 256, 0, stream>>>(bsk, Wp, bp, bpe3);

  for (int l = 0; l < LLL; ++l) {
    const float* We_l = We + (size_t)l*HCC;
    const float* g_l  = gamma + (size_t)l*HIDD;
    const float* b_l  = beta  + (size_t)l*HIDD;

    k1_mfma<<<g1, 256, 0, stream>>>(xb, Wt3 + (size_t)l*1536*128,
                                    biasc3 + (size_t)l*1536, qkvs);
    k23_fused<<<g23, 256, 0, stream>>>(qkvs, rowptr, csr_src, csr_ea, We_l);
    k4_mfma<<<g4, 256, 0, stream>>>(qkvs, xb, Wpt3 + (size_t)l*128*512,
                                    Wskt3 + (size_t)l*128*128, bpe3 + (size_t)l*128,
                                    g_l, b_l, xio, xb, (l == LLL-1) ? 1 : 0);
  }
}